// Round 16
// baseline (399.104 us; speedup 1.0000x reference)
//
#include <hip/hip_runtime.h>
#include <math.h>

// ============ DIAGNOSTIC ROUND: k_pool / k_protos / k_logits run their ============
// ============ bodies 4x (idempotent) to surface in rocprof top-5.      ============
// ============ dur/4 = true time. Revert REP to 1 next round.           ============
#define REP 4

#define B_ 16
#define N_ 4096
#define D_ 512
#define M_ 64
#define MD 32768   // M_*D_

typedef __attribute__((ext_vector_type(4))) float f32x4;
typedef __attribute__((ext_vector_type(8))) short short8;

// ---- workspace layout (float offsets) ----
#define OFF_PSUM   0          // [16][128][512] pooling sum partials (1048576)
#define OFF_PMAXP  1048576    // [16][128][512] pooling max partials (1048576)
#define OFF_CTXB   2097152    // bf16 [16][1024] ctx (8192)
#define OFF_PB     2105344    // bf16 P[b][m*512+d] (262144 floats worth)
#define OFF_WPT    2367488    // bf16 WpT[j][d] = Wp[d][j] (131072)
#define OFF_CB     2498560    // [16][64]
#define OFF_GMAX   2499584    // [16][64]
#define OFF_GINV   2500608    // [16][64]
#define OFF_TPMAX  2501632    // [1024][256] (262144)
#define OFF_TPSUM  2763776    // [1024][256] (262144)
#define OFF_QB     3025920    // bf16 Q'[b][m][c] (262144 floats worth)
#define OFF_LGB    3288064    // bf16 [16][4096][64] (2097152)
// total = 5385216 floats = 21.5 MB

__device__ __forceinline__ unsigned short f2bf(float f) {
    unsigned int u = __float_as_uint(f);
    u += 0x7fffu + ((u >> 16) & 1u);   // round-to-nearest-even
    return (unsigned short)(u >> 16);
}
__device__ __forceinline__ float bf2f(unsigned short u) {
    return __uint_as_float(((unsigned int)u) << 16);
}

// ---- K1: pooling partials. grid 1024 (b*64+nc), block 256 ----
__global__ __launch_bounds__(256) void k_pool(const float* __restrict__ X, float* __restrict__ ws) {
    for (int rep = 0; rep < REP; rep++) {
        asm volatile("" ::: "memory");
        int b = blockIdx.x >> 6, nc = blockIdx.x & 63, t = threadIdx.x;
        int c = t & 127, p = t >> 7;
        const float4* X4 = (const float4*)X;
        float4 s = make_float4(0.f, 0.f, 0.f, 0.f);
        float4 mx = make_float4(-INFINITY, -INFINITY, -INFINITY, -INFINITY);
        int rowbase = b * N_ + nc * 64 + p;
#pragma unroll 8
        for (int i = 0; i < 32; i++) {
            int n = rowbase + 2 * i;
            float4 v = X4[n * 128 + c];
            s.x += v.x; s.y += v.y; s.z += v.z; s.w += v.w;
            mx.x = fmaxf(mx.x, v.x); mx.y = fmaxf(mx.y, v.y);
            mx.z = fmaxf(mx.z, v.z); mx.w = fmaxf(mx.w, v.w);
        }
        int slot = (b * 128 + nc * 2 + p) * 128 + c;   // float4 units
        ((float4*)(ws + OFF_PSUM))[slot] = s;
        ((float4*)(ws + OFF_PMAXP))[slot] = mx;
    }
}

// ---- K2: prep. blocks 0-63: ctx finalize. blocks 64-127: Wp transpose. ----
__global__ __launch_bounds__(256) void k_prep(const float* __restrict__ Wp, float* __restrict__ ws) {
    __shared__ __align__(16) char smem[8448];
    int bx = blockIdx.x, t = threadIdx.x;
    if (bx < 64) {
        f32x4* red = (f32x4*)smem;
        int b = bx >> 2, q = bx & 3;
        int lane = t & 63, w = t >> 6;
        bool isMax = (q >= 2);
        const f32x4* SRC = (const f32x4*)(ws + (isMax ? OFF_PMAXP : OFF_PSUM));
        int kk = (q & 1) * 64 + lane;
        f32x4 acc;
        if (isMax) acc = (f32x4){-INFINITY, -INFINITY, -INFINITY, -INFINITY};
        else       acc = (f32x4){0.f, 0.f, 0.f, 0.f};
#pragma unroll 8
        for (int i = 0; i < 32; i++) {
            int c = w * 32 + i;
            f32x4 v = SRC[(b * 128 + c) * 128 + kk];
            if (isMax) {
                acc[0] = fmaxf(acc[0], v[0]); acc[1] = fmaxf(acc[1], v[1]);
                acc[2] = fmaxf(acc[2], v[2]); acc[3] = fmaxf(acc[3], v[3]);
            } else {
                acc[0] += v[0]; acc[1] += v[1]; acc[2] += v[2]; acc[3] += v[3];
            }
        }
        red[t] = acc;
        __syncthreads();
        if (t < 64) {
            f32x4 a = red[t], b1 = red[64 + t], c1 = red[128 + t], d = red[192 + t];
            f32x4 r;
            if (isMax) {
#pragma unroll
                for (int j = 0; j < 4; j++) r[j] = fmaxf(fmaxf(a[j], b1[j]), fmaxf(c1[j], d[j]));
            } else {
#pragma unroll
                for (int j = 0; j < 4; j++) r[j] = (a[j] + b1[j] + c1[j] + d[j]) * (1.0f / 4096.0f);
            }
            ushort4 o;
            o.x = f2bf(r[0]); o.y = f2bf(r[1]); o.z = f2bf(r[2]); o.w = f2bf(r[3]);
            ((ushort4*)(ws + OFF_CTXB))[b * 256 + q * 64 + t] = o;
        }
    } else {
        unsigned short (*lt)[65] = (unsigned short(*)[65])smem;
        int bb = bx - 64;
        int ti = bb >> 3, tj = bb & 7;
        int sub = t >> 6, lane = t & 63;
#pragma unroll
        for (int i = 0; i < 16; i++) {
            int dl = i * 4 + sub;
            int jl = lane;
            lt[jl][dl] = f2bf(Wp[(ti * 64 + dl) * 512 + tj * 64 + jl]);
        }
        __syncthreads();
        unsigned short* WT = (unsigned short*)(ws + OFF_WPT);
#pragma unroll
        for (int i = 0; i < 16; i++) {
            int jl = i * 4 + sub;
            int dl = lane;
            WT[(tj * 64 + jl) * 512 + ti * 64 + dl] = lt[jl][dl];
        }
    }
}

// ---- K3: P via MFMA -> bf16 Pb. grid 512, block 256. NT loads. ----
__global__ __launch_bounds__(256) void k_protos(const float* __restrict__ Wc, const float* __restrict__ pb,
                                                const float* __restrict__ bc, float* __restrict__ ws) {
    for (int rep = 0; rep < REP; rep++) {
        asm volatile("" ::: "memory");
        int t = threadIdx.x;
        int wave = blockIdx.x * 4 + (t >> 6);   // 0..2047 tiles of 16 W-rows
        int l = t & 63;
        int r0 = wave * 16;
        int row = r0 + (l & 15);                // this lane's W-row (B-frag col)
        int kg = l >> 4;
        const f32x4* W4 = (const f32x4*)Wc;                    // row stride 256 float4
        const short8* CB8 = (const short8*)(ws + OFF_CTXB);    // [16][128] short8 units
        f32x4 acc = (f32x4){0.f, 0.f, 0.f, 0.f};
        int wb = row * 256 + kg * 2;            // float4 idx: k = kg*8
        int cbase = (l & 15) * 128 + kg;        // A-frag: lane&15 = batch row
#pragma unroll 8
        for (int kc = 0; kc < 32; kc++) {
            f32x4 xa = __builtin_nontemporal_load(W4 + wb + kc * 8);
            f32x4 xb = __builtin_nontemporal_load(W4 + wb + kc * 8 + 1);
            short8 wf;
            wf[0] = (short)f2bf(xa[0]); wf[1] = (short)f2bf(xa[1]);
            wf[2] = (short)f2bf(xa[2]); wf[3] = (short)f2bf(xa[3]);
            wf[4] = (short)f2bf(xb[0]); wf[5] = (short)f2bf(xb[1]);
            wf[6] = (short)f2bf(xb[2]); wf[7] = (short)f2bf(xb[3]);
            short8 cf = CB8[cbase + kc * 4];
            acc = __builtin_amdgcn_mfma_f32_16x16x32_bf16(cf, wf, acc, 0, 0, 0);  // A=ctx, B=W
        }
        int r = r0 + (l & 15);
        float add = pb[r] + bc[r];
        unsigned short* Pb = (unsigned short*)(ws + OFF_PB);
#pragma unroll
        for (int i = 0; i < 4; i++) {
            int bb = kg * 4 + i;                // batch
            Pb[bb * MD + r] = f2bf(acc[i] + add);
        }
    }
}

// ---- K4: Q' MFMA (all 512 blocks) + c' fold (blocks 0-255). block 256 ----
__global__ __launch_bounds__(256) void k_q(const float* __restrict__ bpre, float* __restrict__ ws) {
    int t = threadIdx.x;
    int b = blockIdx.x >> 5, ctile = blockIdx.x & 31;
    int mt = t >> 6, l = t & 63;
    int col = l & 15, kg = l >> 4;
    const short8* WT8 = (const short8*)((const unsigned short*)(ws + OFF_WPT));
    const short8* Pb8 = (const short8*)((const unsigned short*)(ws + OFF_PB));
    f32x4 acc = (f32x4){0.f, 0.f, 0.f, 0.f};
    int abase = (ctile * 16 + col) * 64 + kg;        // A: WpT row = j, k = d
    int bbase = (b * 64 + mt * 16 + col) * 64 + kg;  // B: P row = m, k = d
#pragma unroll 4
    for (int kc = 0; kc < 16; kc++) {
        short8 af = WT8[abase + kc * 4];
        short8 bf = Pb8[bbase + kc * 4];
        acc = __builtin_amdgcn_mfma_f32_16x16x32_bf16(af, bf, acc, 0, 0, 0);
    }
    int m = mt * 16 + col;
    unsigned short* Qb = (unsigned short*)(ws + OFF_QB);
    union { unsigned short u[4]; uint2 v; } pk;
#pragma unroll
    for (int i = 0; i < 4; i++) pk.u[i] = f2bf(acc[i] * (1.0f / 64.0f));
    *(uint2*)(Qb + (b * 64 + m) * 512 + ctile * 16 + kg * 4) = pk.v;

    if (blockIdx.x < 256) {                 // c'[b][m] fold
        int w = blockIdx.x * 4 + (t >> 6);  // 0..1023 = b*64+m
        int bb = w >> 6, mm = w & 63;
        const short8* P2 = (const short8*)((const unsigned short*)(ws + OFF_PB) + bb * MD + mm * 512);
        short8 p = P2[l];
        const float4* bp4 = (const float4*)bpre;
        float4 q0 = bp4[l * 2], q1 = bp4[l * 2 + 1];
        float s = bf2f((unsigned short)p[0]) * q0.x + bf2f((unsigned short)p[1]) * q0.y
                + bf2f((unsigned short)p[2]) * q0.z + bf2f((unsigned short)p[3]) * q0.w
                + bf2f((unsigned short)p[4]) * q1.x + bf2f((unsigned short)p[5]) * q1.y
                + bf2f((unsigned short)p[6]) * q1.z + bf2f((unsigned short)p[7]) * q1.w;
#pragma unroll
        for (int off = 1; off < 64; off <<= 1) s += __shfl_xor(s, off);
        if (l == 0) ws[OFF_CB + w] = s * (1.0f / 64.0f);
    }
}

// ---- K5: logits = X.Q'^T + c' via MFMA; LG bf16. grid 1024, block 256 ----
__global__ __launch_bounds__(256) void k_logits(const float* __restrict__ X, float* __restrict__ ws) {
    for (int rep = 0; rep < REP; rep++) {
        asm volatile("" ::: "memory");
        int t = threadIdx.x;
        int W = blockIdx.x * 4 + (t >> 6);   // wave id 0..4095
        int b = W >> 8, nt = W & 255;        // batch, n-tile (16 rows)
        int l = t & 63, col = l & 15, kg = l >> 4;
        int nA = nt * 16 + col;              // A-fragment row
        const float4* X4 = (const float4*)X;
        const short8* Qb8 = (const short8*)((const unsigned short*)(ws + OFF_QB));
        f32x4 acc[4];
#pragma unroll
        for (int mt = 0; mt < 4; mt++) acc[mt] = (f32x4){0.f, 0.f, 0.f, 0.f};

        int xbase4 = ((b * N_ + nA) * D_) >> 2;
        int qbase8 = b * 4096 + col * 64 + kg;  // (b*64+m)*64 short8-units, m = mt*16+col
#pragma unroll 2
        for (int kc = 0; kc < 16; kc++) {
            float4 xa = X4[xbase4 + kc * 8 + kg * 2];
            float4 xb = X4[xbase4 + kc * 8 + kg * 2 + 1];
            short8 af;
            af[0] = (short)f2bf(xa.x); af[1] = (short)f2bf(xa.y);
            af[2] = (short)f2bf(xa.z); af[3] = (short)f2bf(xa.w);
            af[4] = (short)f2bf(xb.x); af[5] = (short)f2bf(xb.y);
            af[6] = (short)f2bf(xb.z); af[7] = (short)f2bf(xb.w);
#pragma unroll
            for (int mt = 0; mt < 4; mt++) {
                short8 bfr = Qb8[qbase8 + mt * 1024 + kc * 4];
                acc[mt] = __builtin_amdgcn_mfma_f32_16x16x32_bf16(af, bfr, acc[mt], 0, 0, 0);
            }
        }
        const float* cb = ws + OFF_CB + b * 64;
        unsigned short* LGB = (unsigned short*)(ws + OFF_LGB) + b * (N_ * 64) + nt * 16 * 64;
#pragma unroll
        for (int mt = 0; mt < 4; mt++) {
            int m = mt * 16 + col;
            float c = cb[m];
            float v0 = acc[mt][0] + c, v1 = acc[mt][1] + c;
            float v2 = acc[mt][2] + c, v3 = acc[mt][3] + c;
            int nr = kg * 4;
            LGB[(nr + 0) * 64 + m] = f2bf(v0);
            LGB[(nr + 1) * 64 + m] = f2bf(v1);
            LGB[(nr + 2) * 64 + m] = f2bf(v2);
            LGB[(nr + 3) * 64 + m] = f2bf(v3);
            float mx = fmaxf(fmaxf(v0, v1), fmaxf(v2, v3));
            mx = fmaxf(mx, __shfl_xor(mx, 16));
            mx = fmaxf(mx, __shfl_xor(mx, 32));
            float s = expf(v0 - mx) + expf(v1 - mx) + expf(v2 - mx) + expf(v3 - mx);
            s += __shfl_xor(s, 16);
            s += __shfl_xor(s, 32);
            if (kg == 0) {
                ws[OFF_TPMAX + (b * 64 + m) * 256 + nt] = mx;
                ws[OFF_TPSUM + (b * 64 + m) * 256 + nt] = s;
            }
        }
    }
}

// ---- K6: combine partials -> gmax, 1/denom. wave per (b,m). grid 256, block 256 ----
__global__ __launch_bounds__(256) void k_combine(float* __restrict__ ws) {
    int t = threadIdx.x;
    int w = blockIdx.x * 4 + (t >> 6);   // 0..1023 = b*64+m
    int l = t & 63;
    float4 a  = ((const float4*)(ws + OFF_TPMAX + w * 256))[l];
    float4 s4 = ((const float4*)(ws + OFF_TPSUM + w * 256))[l];
    float g = fmaxf(fmaxf(a.x, a.y), fmaxf(a.z, a.w));
    float s = s4.x * expf(a.x - g) + s4.y * expf(a.y - g)
            + s4.z * expf(a.z - g) + s4.w * expf(a.w - g);
#pragma unroll
    for (int off = 1; off < 64; off <<= 1) {
        float og = __shfl_xor(g, off);
        float os = __shfl_xor(s, off);
        float ng = fmaxf(g, og);
        s = s * expf(g - ng) + os * expf(og - ng);
        g = ng;
    }
    if (l == 0) { ws[OFF_GMAX + w] = g; ws[OFF_GINV + w] = 1.0f / s; }
}

// ---- K7: out = exp(bf16(l) - gmax) * ginv. grid 2048, block 256 (8 elems/thread) ----
__global__ __launch_bounds__(256) void k_final(const float* __restrict__ ws, float* __restrict__ out) {
    int idx = blockIdx.x * 256 + threadIdx.x;   // uint4 (8 bf16) index
    int flat = idx * 8;
    int b = flat >> 18;                         // / (4096*64)
    int m0 = flat & 63;                         // multiple of 8
    uint4 lg = ((const uint4*)((const unsigned short*)(ws + OFF_LGB)))[idx];
    int bm = b * 64 + m0;
    float4 ga = *(const float4*)(ws + OFF_GMAX + bm);
    float4 gb = *(const float4*)(ws + OFF_GMAX + bm + 4);
    float4 ia = *(const float4*)(ws + OFF_GINV + bm);
    float4 ib = *(const float4*)(ws + OFF_GINV + bm + 4);
    float4 o0, o1;
    o0.x = expf(__uint_as_float(lg.x << 16)         - ga.x) * ia.x;
    o0.y = expf(__uint_as_float(lg.x & 0xffff0000u) - ga.y) * ia.y;
    o0.z = expf(__uint_as_float(lg.y << 16)         - ga.z) * ia.z;
    o0.w = expf(__uint_as_float(lg.y & 0xffff0000u) - ga.w) * ia.w;
    o1.x = expf(__uint_as_float(lg.z << 16)         - gb.x) * ib.x;
    o1.y = expf(__uint_as_float(lg.z & 0xffff0000u) - gb.y) * ib.y;
    o1.z = expf(__uint_as_float(lg.w << 16)         - gb.z) * ib.z;
    o1.w = expf(__uint_as_float(lg.w & 0xffff0000u) - gb.w) * ib.w;
    ((float4*)out)[idx * 2]     = o0;
    ((float4*)out)[idx * 2 + 1] = o1;
}

extern "C" void kernel_launch(void* const* d_in, const int* in_sizes, int n_in,
                              void* d_out, int out_size, void* d_ws, size_t ws_size,
                              hipStream_t stream) {
    const float* X  = (const float*)d_in[0];
    const float* pb = (const float*)d_in[1];
    const float* Wc = (const float*)d_in[2];
    const float* bc = (const float*)d_in[3];
    const float* Wp = (const float*)d_in[4];
    const float* bp = (const float*)d_in[5];
    float* ws  = (float*)d_ws;
    float* out = (float*)d_out;

    k_pool<<<1024, 256, 0, stream>>>(X, ws);
    k_prep<<<128, 256, 0, stream>>>(Wp, ws);
    k_protos<<<512, 256, 0, stream>>>(Wc, pb, bc, ws);
    k_q<<<512, 256, 0, stream>>>(bp, ws);
    k_logits<<<1024, 256, 0, stream>>>(X, ws);
    k_combine<<<256, 256, 0, stream>>>(ws);
    k_final<<<2048, 256, 0, stream>>>(ws, out);
}

// Round 17
// 137.617 us; speedup vs baseline: 2.9001x; 2.9001x over previous
//
#include <hip/hip_runtime.h>
#include <math.h>

#define B_ 16
#define N_ 4096
#define D_ 512
#define M_ 64
#define MD 32768   // M_*D_

typedef __attribute__((ext_vector_type(4))) float f32x4;
typedef __attribute__((ext_vector_type(8))) short short8;

// ---- workspace layout (float offsets) ----
#define OFF_PSUM   0          // [16][128][512] pooling sum partials (1048576)
#define OFF_PMAXP  1048576    // [16][128][512] pooling max partials (1048576)
#define OFF_CTXB   2097152    // bf16 [16][1024] ctx (8192)
#define OFF_PB     2105344    // bf16 P[b][m*512+d] (262144 floats worth)
#define OFF_WPT    2367488    // bf16 WpT[j][d] = Wp[d][j] (131072)
#define OFF_CB     2498560    // [16][64]
#define OFF_GMAX   2499584    // [16][64]
#define OFF_GINV   2500608    // [16][64]
#define OFF_TPMAX  2501632    // [1024][256] (262144)
#define OFF_TPSUM  2763776    // [1024][256] (262144)
#define OFF_QB     3025920    // bf16 Q'[b][m][c] (262144 floats worth)
#define OFF_LGB    3288064    // bf16 [16][4096][64] (2097152)
// total = 5385216 floats = 21.5 MB

__device__ __forceinline__ unsigned short f2bf(float f) {
    unsigned int u = __float_as_uint(f);
    u += 0x7fffu + ((u >> 16) & 1u);   // round-to-nearest-even
    return (unsigned short)(u >> 16);
}
__device__ __forceinline__ float bf2f(unsigned short u) {
    return __uint_as_float(((unsigned int)u) << 16);
}

// ---- K1: pooling partials. grid 1024 (b*64+nc), block 256 ----
__global__ __launch_bounds__(256) void k_pool(const float* __restrict__ X, float* __restrict__ ws) {
    int b = blockIdx.x >> 6, nc = blockIdx.x & 63, t = threadIdx.x;
    int c = t & 127, p = t >> 7;
    const float4* X4 = (const float4*)X;
    float4 s = make_float4(0.f, 0.f, 0.f, 0.f);
    float4 mx = make_float4(-INFINITY, -INFINITY, -INFINITY, -INFINITY);
    int rowbase = b * N_ + nc * 64 + p;
#pragma unroll 8
    for (int i = 0; i < 32; i++) {
        int n = rowbase + 2 * i;
        float4 v = X4[n * 128 + c];
        s.x += v.x; s.y += v.y; s.z += v.z; s.w += v.w;
        mx.x = fmaxf(mx.x, v.x); mx.y = fmaxf(mx.y, v.y);
        mx.z = fmaxf(mx.z, v.z); mx.w = fmaxf(mx.w, v.w);
    }
    int slot = (b * 128 + nc * 2 + p) * 128 + c;   // float4 units
    ((float4*)(ws + OFF_PSUM))[slot] = s;
    ((float4*)(ws + OFF_PMAXP))[slot] = mx;
}

// ---- K2: prep. blocks 0-63: ctx finalize. blocks 64-127: Wp transpose. ----
__global__ __launch_bounds__(256) void k_prep(const float* __restrict__ Wp, float* __restrict__ ws) {
    __shared__ __align__(16) char smem[8448];
    int bx = blockIdx.x, t = threadIdx.x;
    if (bx < 64) {
        f32x4* red = (f32x4*)smem;
        int b = bx >> 2, q = bx & 3;
        int lane = t & 63, w = t >> 6;
        bool isMax = (q >= 2);
        const f32x4* SRC = (const f32x4*)(ws + (isMax ? OFF_PMAXP : OFF_PSUM));
        int kk = (q & 1) * 64 + lane;
        f32x4 acc;
        if (isMax) acc = (f32x4){-INFINITY, -INFINITY, -INFINITY, -INFINITY};
        else       acc = (f32x4){0.f, 0.f, 0.f, 0.f};
#pragma unroll 8
        for (int i = 0; i < 32; i++) {
            int c = w * 32 + i;
            f32x4 v = SRC[(b * 128 + c) * 128 + kk];
            if (isMax) {
                acc[0] = fmaxf(acc[0], v[0]); acc[1] = fmaxf(acc[1], v[1]);
                acc[2] = fmaxf(acc[2], v[2]); acc[3] = fmaxf(acc[3], v[3]);
            } else {
                acc[0] += v[0]; acc[1] += v[1]; acc[2] += v[2]; acc[3] += v[3];
            }
        }
        red[t] = acc;
        __syncthreads();
        if (t < 64) {
            f32x4 a = red[t], b1 = red[64 + t], c1 = red[128 + t], d = red[192 + t];
            f32x4 r;
            if (isMax) {
#pragma unroll
                for (int j = 0; j < 4; j++) r[j] = fmaxf(fmaxf(a[j], b1[j]), fmaxf(c1[j], d[j]));
            } else {
#pragma unroll
                for (int j = 0; j < 4; j++) r[j] = (a[j] + b1[j] + c1[j] + d[j]) * (1.0f / 4096.0f);
            }
            ushort4 o;
            o.x = f2bf(r[0]); o.y = f2bf(r[1]); o.z = f2bf(r[2]); o.w = f2bf(r[3]);
            ((ushort4*)(ws + OFF_CTXB))[b * 256 + q * 64 + t] = o;
        }
    } else {
        unsigned short (*lt)[65] = (unsigned short(*)[65])smem;
        int bb = bx - 64;
        int ti = bb >> 3, tj = bb & 7;
        int sub = t >> 6, lane = t & 63;
#pragma unroll
        for (int i = 0; i < 16; i++) {
            int dl = i * 4 + sub;
            int jl = lane;
            lt[jl][dl] = f2bf(Wp[(ti * 64 + dl) * 512 + tj * 64 + jl]);
        }
        __syncthreads();
        unsigned short* WT = (unsigned short*)(ws + OFF_WPT);
#pragma unroll
        for (int i = 0; i < 16; i++) {
            int jl = i * 4 + sub;
            int dl = lane;
            WT[(tj * 64 + jl) * 512 + ti * 64 + dl] = lt[jl][dl];
        }
    }
}

// ---- K3: P via MFMA -> bf16 Pb. grid 512, block 256. NT loads. ----
__global__ __launch_bounds__(256) void k_protos(const float* __restrict__ Wc, const float* __restrict__ pb,
                                                const float* __restrict__ bc, float* __restrict__ ws) {
    int t = threadIdx.x;
    int wave = blockIdx.x * 4 + (t >> 6);   // 0..2047 tiles of 16 W-rows
    int l = t & 63;
    int r0 = wave * 16;
    int row = r0 + (l & 15);                // this lane's W-row (B-frag col)
    int kg = l >> 4;
    const f32x4* W4 = (const f32x4*)Wc;                    // row stride 256 float4
    const short8* CB8 = (const short8*)(ws + OFF_CTXB);    // [16][128] short8 units
    f32x4 acc = (f32x4){0.f, 0.f, 0.f, 0.f};
    int wb = row * 256 + kg * 2;            // float4 idx: k = kg*8
    int cbase = (l & 15) * 128 + kg;        // A-frag: lane&15 = batch row
#pragma unroll 8
    for (int kc = 0; kc < 32; kc++) {
        f32x4 xa = __builtin_nontemporal_load(W4 + wb + kc * 8);
        f32x4 xb = __builtin_nontemporal_load(W4 + wb + kc * 8 + 1);
        short8 wf;
        wf[0] = (short)f2bf(xa[0]); wf[1] = (short)f2bf(xa[1]);
        wf[2] = (short)f2bf(xa[2]); wf[3] = (short)f2bf(xa[3]);
        wf[4] = (short)f2bf(xb[0]); wf[5] = (short)f2bf(xb[1]);
        wf[6] = (short)f2bf(xb[2]); wf[7] = (short)f2bf(xb[3]);
        short8 cf = CB8[cbase + kc * 4];
        acc = __builtin_amdgcn_mfma_f32_16x16x32_bf16(cf, wf, acc, 0, 0, 0);  // A=ctx, B=W
    }
    int r = r0 + (l & 15);
    float add = pb[r] + bc[r];
    unsigned short* Pb = (unsigned short*)(ws + OFF_PB);
#pragma unroll
    for (int i = 0; i < 4; i++) {
        int bb = kg * 4 + i;                // batch
        Pb[bb * MD + r] = f2bf(acc[i] + add);
    }
}

// ---- K4: Q' MFMA (all 512 blocks) + c' fold (blocks 0-255). block 256 ----
__global__ __launch_bounds__(256) void k_q(const float* __restrict__ bpre, float* __restrict__ ws) {
    int t = threadIdx.x;
    int b = blockIdx.x >> 5, ctile = blockIdx.x & 31;
    int mt = t >> 6, l = t & 63;
    int col = l & 15, kg = l >> 4;
    const short8* WT8 = (const short8*)((const unsigned short*)(ws + OFF_WPT));
    const short8* Pb8 = (const short8*)((const unsigned short*)(ws + OFF_PB));
    f32x4 acc = (f32x4){0.f, 0.f, 0.f, 0.f};
    int abase = (ctile * 16 + col) * 64 + kg;        // A: WpT row = j, k = d
    int bbase = (b * 64 + mt * 16 + col) * 64 + kg;  // B: P row = m, k = d
#pragma unroll 4
    for (int kc = 0; kc < 16; kc++) {
        short8 af = WT8[abase + kc * 4];
        short8 bf = Pb8[bbase + kc * 4];
        acc = __builtin_amdgcn_mfma_f32_16x16x32_bf16(af, bf, acc, 0, 0, 0);
    }
    int m = mt * 16 + col;
    unsigned short* Qb = (unsigned short*)(ws + OFF_QB);
    union { unsigned short u[4]; uint2 v; } pk;
#pragma unroll
    for (int i = 0; i < 4; i++) pk.u[i] = f2bf(acc[i] * (1.0f / 64.0f));
    *(uint2*)(Qb + (b * 64 + m) * 512 + ctile * 16 + kg * 4) = pk.v;

    if (blockIdx.x < 256) {                 // c'[b][m] fold
        int w = blockIdx.x * 4 + (t >> 6);  // 0..1023 = b*64+m
        int bb = w >> 6, mm = w & 63;
        const short8* P2 = (const short8*)((const unsigned short*)(ws + OFF_PB) + bb * MD + mm * 512);
        short8 p = P2[l];
        const float4* bp4 = (const float4*)bpre;
        float4 q0 = bp4[l * 2], q1 = bp4[l * 2 + 1];
        float s = bf2f((unsigned short)p[0]) * q0.x + bf2f((unsigned short)p[1]) * q0.y
                + bf2f((unsigned short)p[2]) * q0.z + bf2f((unsigned short)p[3]) * q0.w
                + bf2f((unsigned short)p[4]) * q1.x + bf2f((unsigned short)p[5]) * q1.y
                + bf2f((unsigned short)p[6]) * q1.z + bf2f((unsigned short)p[7]) * q1.w;
#pragma unroll
        for (int off = 1; off < 64; off <<= 1) s += __shfl_xor(s, off);
        if (l == 0) ws[OFF_CB + w] = s * (1.0f / 64.0f);
    }
}

// ---- K5: logits = X.Q'^T + c' via MFMA; LG bf16. grid 1024, block 256. unroll 4 (MLP). ----
__global__ __launch_bounds__(256) void k_logits(const float* __restrict__ X, float* __restrict__ ws) {
    int t = threadIdx.x;
    int W = blockIdx.x * 4 + (t >> 6);   // wave id 0..4095
    int b = W >> 8, nt = W & 255;        // batch, n-tile (16 rows)
    int l = t & 63, col = l & 15, kg = l >> 4;
    int nA = nt * 16 + col;              // A-fragment row
    const float4* X4 = (const float4*)X;
    const short8* Qb8 = (const short8*)((const unsigned short*)(ws + OFF_QB));
    f32x4 acc[4];
#pragma unroll
    for (int mt = 0; mt < 4; mt++) acc[mt] = (f32x4){0.f, 0.f, 0.f, 0.f};

    int xbase4 = ((b * N_ + nA) * D_) >> 2;
    int qbase8 = b * 4096 + col * 64 + kg;  // (b*64+m)*64 short8-units, m = mt*16+col
#pragma unroll 4
    for (int kc = 0; kc < 16; kc++) {
        float4 xa = X4[xbase4 + kc * 8 + kg * 2];
        float4 xb = X4[xbase4 + kc * 8 + kg * 2 + 1];
        short8 af;
        af[0] = (short)f2bf(xa.x); af[1] = (short)f2bf(xa.y);
        af[2] = (short)f2bf(xa.z); af[3] = (short)f2bf(xa.w);
        af[4] = (short)f2bf(xb.x); af[5] = (short)f2bf(xb.y);
        af[6] = (short)f2bf(xb.z); af[7] = (short)f2bf(xb.w);
#pragma unroll
        for (int mt = 0; mt < 4; mt++) {
            short8 bfr = Qb8[qbase8 + mt * 1024 + kc * 4];
            acc[mt] = __builtin_amdgcn_mfma_f32_16x16x32_bf16(af, bfr, acc[mt], 0, 0, 0);
        }
    }
    const float* cb = ws + OFF_CB + b * 64;
    unsigned short* LGB = (unsigned short*)(ws + OFF_LGB) + b * (N_ * 64) + nt * 16 * 64;
#pragma unroll
    for (int mt = 0; mt < 4; mt++) {
        int m = mt * 16 + col;
        float c = cb[m];
        float v0 = acc[mt][0] + c, v1 = acc[mt][1] + c;
        float v2 = acc[mt][2] + c, v3 = acc[mt][3] + c;
        int nr = kg * 4;
        LGB[(nr + 0) * 64 + m] = f2bf(v0);
        LGB[(nr + 1) * 64 + m] = f2bf(v1);
        LGB[(nr + 2) * 64 + m] = f2bf(v2);
        LGB[(nr + 3) * 64 + m] = f2bf(v3);
        float mx = fmaxf(fmaxf(v0, v1), fmaxf(v2, v3));
        mx = fmaxf(mx, __shfl_xor(mx, 16));
        mx = fmaxf(mx, __shfl_xor(mx, 32));
        float s = expf(v0 - mx) + expf(v1 - mx) + expf(v2 - mx) + expf(v3 - mx);
        s += __shfl_xor(s, 16);
        s += __shfl_xor(s, 32);
        if (kg == 0) {
            ws[OFF_TPMAX + (b * 64 + m) * 256 + nt] = mx;
            ws[OFF_TPSUM + (b * 64 + m) * 256 + nt] = s;
        }
    }
}

// ---- K6: combine partials -> gmax, 1/denom. wave per (b,m). grid 256, block 256 ----
__global__ __launch_bounds__(256) void k_combine(float* __restrict__ ws) {
    int t = threadIdx.x;
    int w = blockIdx.x * 4 + (t >> 6);   // 0..1023 = b*64+m
    int l = t & 63;
    float4 a  = ((const float4*)(ws + OFF_TPMAX + w * 256))[l];
    float4 s4 = ((const float4*)(ws + OFF_TPSUM + w * 256))[l];
    float g = fmaxf(fmaxf(a.x, a.y), fmaxf(a.z, a.w));
    float s = s4.x * expf(a.x - g) + s4.y * expf(a.y - g)
            + s4.z * expf(a.z - g) + s4.w * expf(a.w - g);
#pragma unroll
    for (int off = 1; off < 64; off <<= 1) {
        float og = __shfl_xor(g, off);
        float os = __shfl_xor(s, off);
        float ng = fmaxf(g, og);
        s = s * expf(g - ng) + os * expf(og - ng);
        g = ng;
    }
    if (l == 0) { ws[OFF_GMAX + w] = g; ws[OFF_GINV + w] = 1.0f / s; }
}

// ---- K7: out = exp(bf16(l) - gmax) * ginv. grid 2048, block 256 (8 elems/thread) ----
__global__ __launch_bounds__(256) void k_final(const float* __restrict__ ws, float* __restrict__ out) {
    int idx = blockIdx.x * 256 + threadIdx.x;   // uint4 (8 bf16) index
    int flat = idx * 8;
    int b = flat >> 18;                         // / (4096*64)
    int m0 = flat & 63;                         // multiple of 8
    uint4 lg = ((const uint4*)((const unsigned short*)(ws + OFF_LGB)))[idx];
    int bm = b * 64 + m0;
    float4 ga = *(const float4*)(ws + OFF_GMAX + bm);
    float4 gb = *(const float4*)(ws + OFF_GMAX + bm + 4);
    float4 ia = *(const float4*)(ws + OFF_GINV + bm);
    float4 ib = *(const float4*)(ws + OFF_GINV + bm + 4);
    float4 o0, o1;
    o0.x = expf(__uint_as_float(lg.x << 16)         - ga.x) * ia.x;
    o0.y = expf(__uint_as_float(lg.x & 0xffff0000u) - ga.y) * ia.y;
    o0.z = expf(__uint_as_float(lg.y << 16)         - ga.z) * ia.z;
    o0.w = expf(__uint_as_float(lg.y & 0xffff0000u) - ga.w) * ia.w;
    o1.x = expf(__uint_as_float(lg.z << 16)         - gb.x) * ib.x;
    o1.y = expf(__uint_as_float(lg.z & 0xffff0000u) - gb.y) * ib.y;
    o1.z = expf(__uint_as_float(lg.w << 16)         - gb.z) * ib.z;
    o1.w = expf(__uint_as_float(lg.w & 0xffff0000u) - gb.w) * ib.w;
    ((float4*)out)[idx * 2]     = o0;
    ((float4*)out)[idx * 2 + 1] = o1;
}

extern "C" void kernel_launch(void* const* d_in, const int* in_sizes, int n_in,
                              void* d_out, int out_size, void* d_ws, size_t ws_size,
                              hipStream_t stream) {
    const float* X  = (const float*)d_in[0];
    const float* pb = (const float*)d_in[1];
    const float* Wc = (const float*)d_in[2];
    const float* bc = (const float*)d_in[3];
    const float* Wp = (const float*)d_in[4];
    const float* bp = (const float*)d_in[5];
    float* ws  = (float*)d_ws;
    float* out = (float*)d_out;

    k_pool<<<1024, 256, 0, stream>>>(X, ws);
    k_prep<<<128, 256, 0, stream>>>(Wp, ws);
    k_protos<<<512, 256, 0, stream>>>(Wc, pb, bc, ws);
    k_q<<<512, 256, 0, stream>>>(bp, ws);
    k_logits<<<1024, 256, 0, stream>>>(X, ws);
    k_combine<<<256, 256, 0, stream>>>(ws);
    k_final<<<2048, 256, 0, stream>>>(ws, out);
}

// Round 18
// 137.380 us; speedup vs baseline: 2.9051x; 1.0017x over previous
//
#include <hip/hip_runtime.h>
#include <math.h>

#define B_ 16
#define N_ 4096
#define D_ 512
#define M_ 64
#define MD 32768   // M_*D_

typedef __attribute__((ext_vector_type(4))) float f32x4;
typedef __attribute__((ext_vector_type(8))) short short8;

// ---- workspace layout (float offsets) ----
#define OFF_PSUM   0          // [16][128][512] pooling sum partials (1048576)
#define OFF_PMAXP  1048576    // [16][128][512] pooling max partials (1048576)
#define OFF_CTXB   2097152    // bf16 [16][1024] ctx (8192)
#define OFF_PB     2105344    // bf16 P[b][m*512+d] (262144 floats worth)
#define OFF_WPT    2367488    // bf16 WpT[j][d] = Wp[d][j] (131072)
#define OFF_CB     2498560    // [16][64]
#define OFF_GMAX   2499584    // [16][64]
#define OFF_GINV   2500608    // [16][64]
#define OFF_TPMAX  2501632    // [1024][256] (262144)
#define OFF_TPSUM  2763776    // [1024][256] (262144)
#define OFF_QB     3025920    // bf16 Q'[b][m][c] (262144 floats worth)
#define OFF_LGB    3288064    // bf16 [16][4096][64] (2097152)
// total = 5385216 floats = 21.5 MB

__device__ __forceinline__ unsigned short f2bf(float f) {
    unsigned int u = __float_as_uint(f);
    u += 0x7fffu + ((u >> 16) & 1u);   // round-to-nearest-even
    return (unsigned short)(u >> 16);
}
__device__ __forceinline__ float bf2f(unsigned short u) {
    return __uint_as_float(((unsigned int)u) << 16);
}

// ---- K1: pooling partials. grid 1024 (b*64+nc), block 256 ----
__global__ __launch_bounds__(256) void k_pool(const float* __restrict__ X, float* __restrict__ ws) {
    int b = blockIdx.x >> 6, nc = blockIdx.x & 63, t = threadIdx.x;
    int c = t & 127, p = t >> 7;
    const float4* X4 = (const float4*)X;
    float4 s = make_float4(0.f, 0.f, 0.f, 0.f);
    float4 mx = make_float4(-INFINITY, -INFINITY, -INFINITY, -INFINITY);
    int rowbase = b * N_ + nc * 64 + p;
#pragma unroll 8
    for (int i = 0; i < 32; i++) {
        int n = rowbase + 2 * i;
        float4 v = X4[n * 128 + c];
        s.x += v.x; s.y += v.y; s.z += v.z; s.w += v.w;
        mx.x = fmaxf(mx.x, v.x); mx.y = fmaxf(mx.y, v.y);
        mx.z = fmaxf(mx.z, v.z); mx.w = fmaxf(mx.w, v.w);
    }
    int slot = (b * 128 + nc * 2 + p) * 128 + c;   // float4 units
    ((float4*)(ws + OFF_PSUM))[slot] = s;
    ((float4*)(ws + OFF_PMAXP))[slot] = mx;
}

// ---- K2: prep. blocks 0-63: ctx finalize. blocks 64-127: Wp transpose. ----
__global__ __launch_bounds__(256) void k_prep(const float* __restrict__ Wp, float* __restrict__ ws) {
    __shared__ __align__(16) char smem[8448];
    int bx = blockIdx.x, t = threadIdx.x;
    if (bx < 64) {
        f32x4* red = (f32x4*)smem;
        int b = bx >> 2, q = bx & 3;
        int lane = t & 63, w = t >> 6;
        bool isMax = (q >= 2);
        const f32x4* SRC = (const f32x4*)(ws + (isMax ? OFF_PMAXP : OFF_PSUM));
        int kk = (q & 1) * 64 + lane;
        f32x4 acc;
        if (isMax) acc = (f32x4){-INFINITY, -INFINITY, -INFINITY, -INFINITY};
        else       acc = (f32x4){0.f, 0.f, 0.f, 0.f};
#pragma unroll 8
        for (int i = 0; i < 32; i++) {
            int c = w * 32 + i;
            f32x4 v = SRC[(b * 128 + c) * 128 + kk];
            if (isMax) {
                acc[0] = fmaxf(acc[0], v[0]); acc[1] = fmaxf(acc[1], v[1]);
                acc[2] = fmaxf(acc[2], v[2]); acc[3] = fmaxf(acc[3], v[3]);
            } else {
                acc[0] += v[0]; acc[1] += v[1]; acc[2] += v[2]; acc[3] += v[3];
            }
        }
        red[t] = acc;
        __syncthreads();
        if (t < 64) {
            f32x4 a = red[t], b1 = red[64 + t], c1 = red[128 + t], d = red[192 + t];
            f32x4 r;
            if (isMax) {
#pragma unroll
                for (int j = 0; j < 4; j++) r[j] = fmaxf(fmaxf(a[j], b1[j]), fmaxf(c1[j], d[j]));
            } else {
#pragma unroll
                for (int j = 0; j < 4; j++) r[j] = (a[j] + b1[j] + c1[j] + d[j]) * (1.0f / 4096.0f);
            }
            ushort4 o;
            o.x = f2bf(r[0]); o.y = f2bf(r[1]); o.z = f2bf(r[2]); o.w = f2bf(r[3]);
            ((ushort4*)(ws + OFF_CTXB))[b * 256 + q * 64 + t] = o;
        }
    } else {
        unsigned short (*lt)[65] = (unsigned short(*)[65])smem;
        int bb = bx - 64;
        int ti = bb >> 3, tj = bb & 7;
        int sub = t >> 6, lane = t & 63;
#pragma unroll
        for (int i = 0; i < 16; i++) {
            int dl = i * 4 + sub;
            int jl = lane;
            lt[jl][dl] = f2bf(Wp[(ti * 64 + dl) * 512 + tj * 64 + jl]);
        }
        __syncthreads();
        unsigned short* WT = (unsigned short*)(ws + OFF_WPT);
#pragma unroll
        for (int i = 0; i < 16; i++) {
            int jl = i * 4 + sub;
            int dl = lane;
            WT[(tj * 64 + jl) * 512 + ti * 64 + dl] = lt[jl][dl];
        }
    }
}

// ---- K3: P via MFMA -> bf16 Pb. grid 512, block 256. NT loads. ----
__global__ __launch_bounds__(256) void k_protos(const float* __restrict__ Wc, const float* __restrict__ pb,
                                                const float* __restrict__ bc, float* __restrict__ ws) {
    int t = threadIdx.x;
    int wave = blockIdx.x * 4 + (t >> 6);   // 0..2047 tiles of 16 W-rows
    int l = t & 63;
    int r0 = wave * 16;
    int row = r0 + (l & 15);                // this lane's W-row (B-frag col)
    int kg = l >> 4;
    const f32x4* W4 = (const f32x4*)Wc;                    // row stride 256 float4
    const short8* CB8 = (const short8*)(ws + OFF_CTXB);    // [16][128] short8 units
    f32x4 acc = (f32x4){0.f, 0.f, 0.f, 0.f};
    int wb = row * 256 + kg * 2;            // float4 idx: k = kg*8
    int cbase = (l & 15) * 128 + kg;        // A-frag: lane&15 = batch row
#pragma unroll 8
    for (int kc = 0; kc < 32; kc++) {
        f32x4 xa = __builtin_nontemporal_load(W4 + wb + kc * 8);
        f32x4 xb = __builtin_nontemporal_load(W4 + wb + kc * 8 + 1);
        short8 wf;
        wf[0] = (short)f2bf(xa[0]); wf[1] = (short)f2bf(xa[1]);
        wf[2] = (short)f2bf(xa[2]); wf[3] = (short)f2bf(xa[3]);
        wf[4] = (short)f2bf(xb[0]); wf[5] = (short)f2bf(xb[1]);
        wf[6] = (short)f2bf(xb[2]); wf[7] = (short)f2bf(xb[3]);
        short8 cf = CB8[cbase + kc * 4];
        acc = __builtin_amdgcn_mfma_f32_16x16x32_bf16(cf, wf, acc, 0, 0, 0);  // A=ctx, B=W
    }
    int r = r0 + (l & 15);
    float add = pb[r] + bc[r];
    unsigned short* Pb = (unsigned short*)(ws + OFF_PB);
#pragma unroll
    for (int i = 0; i < 4; i++) {
        int bb = kg * 4 + i;                // batch
        Pb[bb * MD + r] = f2bf(acc[i] + add);
    }
}

// ---- K4: Q' MFMA (all 512 blocks) + c' fold (blocks 0-255). block 256 ----
__global__ __launch_bounds__(256) void k_q(const float* __restrict__ bpre, float* __restrict__ ws) {
    int t = threadIdx.x;
    int b = blockIdx.x >> 5, ctile = blockIdx.x & 31;
    int mt = t >> 6, l = t & 63;
    int col = l & 15, kg = l >> 4;
    const short8* WT8 = (const short8*)((const unsigned short*)(ws + OFF_WPT));
    const short8* Pb8 = (const short8*)((const unsigned short*)(ws + OFF_PB));
    f32x4 acc = (f32x4){0.f, 0.f, 0.f, 0.f};
    int abase = (ctile * 16 + col) * 64 + kg;        // A: WpT row = j, k = d
    int bbase = (b * 64 + mt * 16 + col) * 64 + kg;  // B: P row = m, k = d
#pragma unroll 4
    for (int kc = 0; kc < 16; kc++) {
        short8 af = WT8[abase + kc * 4];
        short8 bf = Pb8[bbase + kc * 4];
        acc = __builtin_amdgcn_mfma_f32_16x16x32_bf16(af, bf, acc, 0, 0, 0);
    }
    int m = mt * 16 + col;
    unsigned short* Qb = (unsigned short*)(ws + OFF_QB);
    union { unsigned short u[4]; uint2 v; } pk;
#pragma unroll
    for (int i = 0; i < 4; i++) pk.u[i] = f2bf(acc[i] * (1.0f / 64.0f));
    *(uint2*)(Qb + (b * 64 + m) * 512 + ctile * 16 + kg * 4) = pk.v;

    if (blockIdx.x < 256) {                 // c'[b][m] fold
        int w = blockIdx.x * 4 + (t >> 6);  // 0..1023 = b*64+m
        int bb = w >> 6, mm = w & 63;
        const short8* P2 = (const short8*)((const unsigned short*)(ws + OFF_PB) + bb * MD + mm * 512);
        short8 p = P2[l];
        const float4* bp4 = (const float4*)bpre;
        float4 q0 = bp4[l * 2], q1 = bp4[l * 2 + 1];
        float s = bf2f((unsigned short)p[0]) * q0.x + bf2f((unsigned short)p[1]) * q0.y
                + bf2f((unsigned short)p[2]) * q0.z + bf2f((unsigned short)p[3]) * q0.w
                + bf2f((unsigned short)p[4]) * q1.x + bf2f((unsigned short)p[5]) * q1.y
                + bf2f((unsigned short)p[6]) * q1.z + bf2f((unsigned short)p[7]) * q1.w;
#pragma unroll
        for (int off = 1; off < 64; off <<= 1) s += __shfl_xor(s, off);
        if (l == 0) ws[OFF_CB + w] = s * (1.0f / 64.0f);
    }
}

// ---- K5: logits via MFMA with 8-deep explicit X prefetch pipeline. grid 1024, block 256 ----
__global__ __launch_bounds__(256) void k_logits(const float* __restrict__ X, float* __restrict__ ws) {
    int t = threadIdx.x;
    int W = blockIdx.x * 4 + (t >> 6);   // wave id 0..4095
    int b = W >> 8, nt = W & 255;        // batch, n-tile (16 rows)
    int l = t & 63, col = l & 15, kg = l >> 4;
    int nA = nt * 16 + col;              // A-fragment row
    const float4* X4 = (const float4*)X;
    const short8* Qb8 = (const short8*)((const unsigned short*)(ws + OFF_QB));
    f32x4 acc[4];
#pragma unroll
    for (int mt = 0; mt < 4; mt++) acc[mt] = (f32x4){0.f, 0.f, 0.f, 0.f};

    int xbase4 = ((b * N_ + nA) * D_) >> 2;
    int qbase8 = b * 4096 + col * 64 + kg;  // (b*64+m)*64 short8-units, m = mt*16+col

    // 8-deep register prefetch pipeline for X (forces ~16 loads in flight)
    float4 pxa[8], pxb[8];
#pragma unroll
    for (int i = 0; i < 8; i++) {
        pxa[i] = X4[xbase4 + i * 8 + kg * 2];
        pxb[i] = X4[xbase4 + i * 8 + kg * 2 + 1];
    }
#pragma unroll
    for (int kc = 0; kc < 16; kc++) {
        float4 xa = pxa[kc & 7];
        float4 xb = pxb[kc & 7];
        if (kc < 8) {
            pxa[kc & 7] = X4[xbase4 + (kc + 8) * 8 + kg * 2];
            pxb[kc & 7] = X4[xbase4 + (kc + 8) * 8 + kg * 2 + 1];
        }
        short8 af;
        af[0] = (short)f2bf(xa.x); af[1] = (short)f2bf(xa.y);
        af[2] = (short)f2bf(xa.z); af[3] = (short)f2bf(xa.w);
        af[4] = (short)f2bf(xb.x); af[5] = (short)f2bf(xb.y);
        af[6] = (short)f2bf(xb.z); af[7] = (short)f2bf(xb.w);
#pragma unroll
        for (int mt = 0; mt < 4; mt++) {
            short8 bfr = Qb8[qbase8 + mt * 1024 + kc * 4];
            acc[mt] = __builtin_amdgcn_mfma_f32_16x16x32_bf16(af, bfr, acc[mt], 0, 0, 0);
        }
    }
    const float* cb = ws + OFF_CB + b * 64;
    unsigned short* LGB = (unsigned short*)(ws + OFF_LGB) + b * (N_ * 64) + nt * 16 * 64;
#pragma unroll
    for (int mt = 0; mt < 4; mt++) {
        int m = mt * 16 + col;
        float c = cb[m];
        float v0 = acc[mt][0] + c, v1 = acc[mt][1] + c;
        float v2 = acc[mt][2] + c, v3 = acc[mt][3] + c;
        int nr = kg * 4;
        LGB[(nr + 0) * 64 + m] = f2bf(v0);
        LGB[(nr + 1) * 64 + m] = f2bf(v1);
        LGB[(nr + 2) * 64 + m] = f2bf(v2);
        LGB[(nr + 3) * 64 + m] = f2bf(v3);
        float mx = fmaxf(fmaxf(v0, v1), fmaxf(v2, v3));
        mx = fmaxf(mx, __shfl_xor(mx, 16));
        mx = fmaxf(mx, __shfl_xor(mx, 32));
        float s = expf(v0 - mx) + expf(v1 - mx) + expf(v2 - mx) + expf(v3 - mx);
        s += __shfl_xor(s, 16);
        s += __shfl_xor(s, 32);
        if (kg == 0) {
            ws[OFF_TPMAX + (b * 64 + m) * 256 + nt] = mx;
            ws[OFF_TPSUM + (b * 64 + m) * 256 + nt] = s;
        }
    }
}

// ---- K6: combine partials -> gmax, 1/denom. wave per (b,m). grid 256, block 256 ----
__global__ __launch_bounds__(256) void k_combine(float* __restrict__ ws) {
    int t = threadIdx.x;
    int w = blockIdx.x * 4 + (t >> 6);   // 0..1023 = b*64+m
    int l = t & 63;
    float4 a  = ((const float4*)(ws + OFF_TPMAX + w * 256))[l];
    float4 s4 = ((const float4*)(ws + OFF_TPSUM + w * 256))[l];
    float g = fmaxf(fmaxf(a.x, a.y), fmaxf(a.z, a.w));
    float s = s4.x * expf(a.x - g) + s4.y * expf(a.y - g)
            + s4.z * expf(a.z - g) + s4.w * expf(a.w - g);
#pragma unroll
    for (int off = 1; off < 64; off <<= 1) {
        float og = __shfl_xor(g, off);
        float os = __shfl_xor(s, off);
        float ng = fmaxf(g, og);
        s = s * expf(g - ng) + os * expf(og - ng);
        g = ng;
    }
    if (l == 0) { ws[OFF_GMAX + w] = g; ws[OFF_GINV + w] = 1.0f / s; }
}

// ---- K7: out = exp(bf16(l) - gmax) * ginv. grid 2048, block 256 (8 elems/thread) ----
__global__ __launch_bounds__(256) void k_final(const float* __restrict__ ws, float* __restrict__ out) {
    int idx = blockIdx.x * 256 + threadIdx.x;   // uint4 (8 bf16) index
    int flat = idx * 8;
    int b = flat >> 18;                         // / (4096*64)
    int m0 = flat & 63;                         // multiple of 8
    uint4 lg = ((const uint4*)((const unsigned short*)(ws + OFF_LGB)))[idx];
    int bm = b * 64 + m0;
    float4 ga = *(const float4*)(ws + OFF_GMAX + bm);
    float4 gb = *(const float4*)(ws + OFF_GMAX + bm + 4);
    float4 ia = *(const float4*)(ws + OFF_GINV + bm);
    float4 ib = *(const float4*)(ws + OFF_GINV + bm + 4);
    float4 o0, o1;
    o0.x = expf(__uint_as_float(lg.x << 16)         - ga.x) * ia.x;
    o0.y = expf(__uint_as_float(lg.x & 0xffff0000u) - ga.y) * ia.y;
    o0.z = expf(__uint_as_float(lg.y << 16)         - ga.z) * ia.z;
    o0.w = expf(__uint_as_float(lg.y & 0xffff0000u) - ga.w) * ia.w;
    o1.x = expf(__uint_as_float(lg.z << 16)         - gb.x) * ib.x;
    o1.y = expf(__uint_as_float(lg.z & 0xffff0000u) - gb.y) * ib.y;
    o1.z = expf(__uint_as_float(lg.w << 16)         - gb.z) * ib.z;
    o1.w = expf(__uint_as_float(lg.w & 0xffff0000u) - gb.w) * ib.w;
    ((float4*)out)[idx * 2]     = o0;
    ((float4*)out)[idx * 2 + 1] = o1;
}

extern "C" void kernel_launch(void* const* d_in, const int* in_sizes, int n_in,
                              void* d_out, int out_size, void* d_ws, size_t ws_size,
                              hipStream_t stream) {
    const float* X  = (const float*)d_in[0];
    const float* pb = (const float*)d_in[1];
    const float* Wc = (const float*)d_in[2];
    const float* bc = (const float*)d_in[3];
    const float* Wp = (const float*)d_in[4];
    const float* bp = (const float*)d_in[5];
    float* ws  = (float*)d_ws;
    float* out = (float*)d_out;

    k_pool<<<1024, 256, 0, stream>>>(X, ws);
    k_prep<<<128, 256, 0, stream>>>(Wp, ws);
    k_protos<<<512, 256, 0, stream>>>(Wc, pb, bc, ws);
    k_q<<<512, 256, 0, stream>>>(bp, ws);
    k_logits<<<1024, 256, 0, stream>>>(X, ws);
    k_combine<<<256, 256, 0, stream>>>(ws);
    k_final<<<2048, 256, 0, stream>>>(ws, out);
}

// Round 19
// 119.020 us; speedup vs baseline: 3.3533x; 1.1543x over previous
//
#include <hip/hip_runtime.h>
#include <math.h>

#define B_ 16
#define N_ 4096
#define D_ 512
#define M_ 64
#define MD 32768   // M_*D_

typedef __attribute__((ext_vector_type(4))) float f32x4;
typedef __attribute__((ext_vector_type(8))) short short8;

// ---- workspace layout (float offsets) ----
#define OFF_PSUM   0          // [16][128][512] pooling sum partials (1048576)
#define OFF_PMAXP  1048576    // [16][128][512] pooling max partials (1048576)
#define OFF_CTXB   2097152    // bf16 [16][1024] ctx (8192)
#define OFF_PB     2105344    // bf16 P[b][m*512+d] (262144 floats worth)
#define OFF_WPT    2367488    // bf16 WpT[j][d] = Wp[d][j] (131072)
#define OFF_CB     2498560    // [16][64]
#define OFF_GMAX   2499584    // [16][64]
#define OFF_GINV   2500608    // [16][64]
#define OFF_TPMAX  2501632    // [1024][256] (262144)
#define OFF_TPSUM  2763776    // [1024][256] (262144)
#define OFF_QB     3025920    // bf16 Q' FRAGMENT-MAJOR [b][kc][mt][lane] short8 (262144 floats)
#define OFF_LGB    3288064    // bf16 [16][4096][64] (2097152)
// total = 5385216 floats = 21.5 MB

__device__ __forceinline__ unsigned short f2bf(float f) {
    unsigned int u = __float_as_uint(f);
    u += 0x7fffu + ((u >> 16) & 1u);   // round-to-nearest-even
    return (unsigned short)(u >> 16);
}
__device__ __forceinline__ float bf2f(unsigned short u) {
    return __uint_as_float(((unsigned int)u) << 16);
}

// ---- K1: pooling partials. grid 1024 (b*64+nc), block 256 ----
__global__ __launch_bounds__(256) void k_pool(const float* __restrict__ X, float* __restrict__ ws) {
    int b = blockIdx.x >> 6, nc = blockIdx.x & 63, t = threadIdx.x;
    int c = t & 127, p = t >> 7;
    const float4* X4 = (const float4*)X;
    float4 s = make_float4(0.f, 0.f, 0.f, 0.f);
    float4 mx = make_float4(-INFINITY, -INFINITY, -INFINITY, -INFINITY);
    int rowbase = b * N_ + nc * 64 + p;
#pragma unroll 8
    for (int i = 0; i < 32; i++) {
        int n = rowbase + 2 * i;
        float4 v = X4[n * 128 + c];
        s.x += v.x; s.y += v.y; s.z += v.z; s.w += v.w;
        mx.x = fmaxf(mx.x, v.x); mx.y = fmaxf(mx.y, v.y);
        mx.z = fmaxf(mx.z, v.z); mx.w = fmaxf(mx.w, v.w);
    }
    int slot = (b * 128 + nc * 2 + p) * 128 + c;   // float4 units
    ((float4*)(ws + OFF_PSUM))[slot] = s;
    ((float4*)(ws + OFF_PMAXP))[slot] = mx;
}

// ---- K2: prep. blocks 0-63: ctx finalize. blocks 64-127: Wp transpose. ----
__global__ __launch_bounds__(256) void k_prep(const float* __restrict__ Wp, float* __restrict__ ws) {
    __shared__ __align__(16) char smem[8448];
    int bx = blockIdx.x, t = threadIdx.x;
    if (bx < 64) {
        f32x4* red = (f32x4*)smem;
        int b = bx >> 2, q = bx & 3;
        int lane = t & 63, w = t >> 6;
        bool isMax = (q >= 2);
        const f32x4* SRC = (const f32x4*)(ws + (isMax ? OFF_PMAXP : OFF_PSUM));
        int kk = (q & 1) * 64 + lane;
        f32x4 acc;
        if (isMax) acc = (f32x4){-INFINITY, -INFINITY, -INFINITY, -INFINITY};
        else       acc = (f32x4){0.f, 0.f, 0.f, 0.f};
#pragma unroll 8
        for (int i = 0; i < 32; i++) {
            int c = w * 32 + i;
            f32x4 v = SRC[(b * 128 + c) * 128 + kk];
            if (isMax) {
                acc[0] = fmaxf(acc[0], v[0]); acc[1] = fmaxf(acc[1], v[1]);
                acc[2] = fmaxf(acc[2], v[2]); acc[3] = fmaxf(acc[3], v[3]);
            } else {
                acc[0] += v[0]; acc[1] += v[1]; acc[2] += v[2]; acc[3] += v[3];
            }
        }
        red[t] = acc;
        __syncthreads();
        if (t < 64) {
            f32x4 a = red[t], b1 = red[64 + t], c1 = red[128 + t], d = red[192 + t];
            f32x4 r;
            if (isMax) {
#pragma unroll
                for (int j = 0; j < 4; j++) r[j] = fmaxf(fmaxf(a[j], b1[j]), fmaxf(c1[j], d[j]));
            } else {
#pragma unroll
                for (int j = 0; j < 4; j++) r[j] = (a[j] + b1[j] + c1[j] + d[j]) * (1.0f / 4096.0f);
            }
            ushort4 o;
            o.x = f2bf(r[0]); o.y = f2bf(r[1]); o.z = f2bf(r[2]); o.w = f2bf(r[3]);
            ((ushort4*)(ws + OFF_CTXB))[b * 256 + q * 64 + t] = o;
        }
    } else {
        unsigned short (*lt)[65] = (unsigned short(*)[65])smem;
        int bb = bx - 64;
        int ti = bb >> 3, tj = bb & 7;
        int sub = t >> 6, lane = t & 63;
#pragma unroll
        for (int i = 0; i < 16; i++) {
            int dl = i * 4 + sub;
            int jl = lane;
            lt[jl][dl] = f2bf(Wp[(ti * 64 + dl) * 512 + tj * 64 + jl]);
        }
        __syncthreads();
        unsigned short* WT = (unsigned short*)(ws + OFF_WPT);
#pragma unroll
        for (int i = 0; i < 16; i++) {
            int jl = i * 4 + sub;
            int dl = lane;
            WT[(tj * 64 + jl) * 512 + ti * 64 + dl] = lt[jl][dl];
        }
    }
}

// ---- K3: P via MFMA -> bf16 Pb. grid 512, block 256. NT loads. ----
__global__ __launch_bounds__(256) void k_protos(const float* __restrict__ Wc, const float* __restrict__ pb,
                                                const float* __restrict__ bc, float* __restrict__ ws) {
    int t = threadIdx.x;
    int wave = blockIdx.x * 4 + (t >> 6);   // 0..2047 tiles of 16 W-rows
    int l = t & 63;
    int r0 = wave * 16;
    int row = r0 + (l & 15);                // this lane's W-row (B-frag col)
    int kg = l >> 4;
    const f32x4* W4 = (const f32x4*)Wc;                    // row stride 256 float4
    const short8* CB8 = (const short8*)(ws + OFF_CTXB);    // [16][128] short8 units
    f32x4 acc = (f32x4){0.f, 0.f, 0.f, 0.f};
    int wb = row * 256 + kg * 2;            // float4 idx: k = kg*8
    int cbase = (l & 15) * 128 + kg;        // A-frag: lane&15 = batch row
#pragma unroll 8
    for (int kc = 0; kc < 32; kc++) {
        f32x4 xa = __builtin_nontemporal_load(W4 + wb + kc * 8);
        f32x4 xb = __builtin_nontemporal_load(W4 + wb + kc * 8 + 1);
        short8 wf;
        wf[0] = (short)f2bf(xa[0]); wf[1] = (short)f2bf(xa[1]);
        wf[2] = (short)f2bf(xa[2]); wf[3] = (short)f2bf(xa[3]);
        wf[4] = (short)f2bf(xb[0]); wf[5] = (short)f2bf(xb[1]);
        wf[6] = (short)f2bf(xb[2]); wf[7] = (short)f2bf(xb[3]);
        short8 cf = CB8[cbase + kc * 4];
        acc = __builtin_amdgcn_mfma_f32_16x16x32_bf16(cf, wf, acc, 0, 0, 0);  // A=ctx, B=W
    }
    int r = r0 + (l & 15);
    float add = pb[r] + bc[r];
    unsigned short* Pb = (unsigned short*)(ws + OFF_PB);
#pragma unroll
    for (int i = 0; i < 4; i++) {
        int bb = kg * 4 + i;                // batch
        Pb[bb * MD + r] = f2bf(acc[i] + add);
    }
}

// ---- K4: Q' MFMA -> fragment-major Qb + c' fold (blocks 0-255). grid 512, block 256 ----
__global__ __launch_bounds__(256) void k_q(const float* __restrict__ bpre, float* __restrict__ ws) {
    int t = threadIdx.x;
    int b = blockIdx.x >> 5, ctile = blockIdx.x & 31;
    int mt = t >> 6, l = t & 63;
    int col = l & 15, kg = l >> 4;
    const short8* WT8 = (const short8*)((const unsigned short*)(ws + OFF_WPT));
    const short8* Pb8 = (const short8*)((const unsigned short*)(ws + OFF_PB));
    f32x4 acc = (f32x4){0.f, 0.f, 0.f, 0.f};
    int abase = (ctile * 16 + col) * 64 + kg;        // A: WpT row = j, k = d
    int bbase = (b * 64 + mt * 16 + col) * 64 + kg;  // B: P row = m, k = d
#pragma unroll 4
    for (int kc = 0; kc < 16; kc++) {
        short8 af = WT8[abase + kc * 4];
        short8 bf = Pb8[bbase + kc * 4];
        acc = __builtin_amdgcn_mfma_f32_16x16x32_bf16(af, bf, acc, 0, 0, 0);
    }
    // D[j = ctile*16 + kg*4 + i][m = mt*16+col] -> fragment-major Qb:
    // frag kc=ctile>>1, lane-group g=(ctile&1)*2+(kg>>1), uint2 sub kg&1
    union { unsigned short u[4]; uint2 v; } pk;
#pragma unroll
    for (int i = 0; i < 4; i++) pk.u[i] = f2bf(acc[i] * (1.0f / 64.0f));
    int g = (ctile & 1) * 2 + (kg >> 1);
    int fidx = b * 4096 + ((ctile >> 1) * 4 + mt) * 64 + g * 16 + col;   // short8 units
    ((uint2*)((unsigned short*)(ws + OFF_QB)))[fidx * 2 + (kg & 1)] = pk.v;

    if (blockIdx.x < 256) {                 // c'[b][m] fold
        int w = blockIdx.x * 4 + (t >> 6);  // 0..1023 = b*64+m
        int bb = w >> 6, mm = w & 63;
        const short8* P2 = (const short8*)((const unsigned short*)(ws + OFF_PB) + bb * MD + mm * 512);
        short8 p = P2[l];
        const float4* bp4 = (const float4*)bpre;
        float4 q0 = bp4[l * 2], q1 = bp4[l * 2 + 1];
        float s = bf2f((unsigned short)p[0]) * q0.x + bf2f((unsigned short)p[1]) * q0.y
                + bf2f((unsigned short)p[2]) * q0.z + bf2f((unsigned short)p[3]) * q0.w
                + bf2f((unsigned short)p[4]) * q1.x + bf2f((unsigned short)p[5]) * q1.y
                + bf2f((unsigned short)p[6]) * q1.z + bf2f((unsigned short)p[7]) * q1.w;
#pragma unroll
        for (int off = 1; off < 64; off <<= 1) s += __shfl_xor(s, off);
        if (l == 0) ws[OFF_CB + w] = s * (1.0f / 64.0f);
    }
}

// ---- K5: logits via MFMA; Qb fragment-major coalesced loads. grid 1024, block 256 ----
__global__ __launch_bounds__(256) void k_logits(const float* __restrict__ X, float* __restrict__ ws) {
    int t = threadIdx.x;
    int W = blockIdx.x * 4 + (t >> 6);   // wave id 0..4095
    int b = W >> 8, nt = W & 255;        // batch, n-tile (16 rows)
    int l = t & 63, col = l & 15, kg = l >> 4;
    int nA = nt * 16 + col;              // A-fragment row
    const float4* X4 = (const float4*)X;
    const short8* Qb8 = (const short8*)((const unsigned short*)(ws + OFF_QB));
    f32x4 acc[4];
#pragma unroll
    for (int mt = 0; mt < 4; mt++) acc[mt] = (f32x4){0.f, 0.f, 0.f, 0.f};

    int xbase4 = ((b * N_ + nA) * D_) >> 2;
    int qfrag = b * 4096 + l;            // + (kc*4+mt)*64 : lane-linear coalesced

    // 8-deep register prefetch pipeline for X
    float4 pxa[8], pxb[8];
#pragma unroll
    for (int i = 0; i < 8; i++) {
        pxa[i] = X4[xbase4 + i * 8 + kg * 2];
        pxb[i] = X4[xbase4 + i * 8 + kg * 2 + 1];
    }
#pragma unroll
    for (int kc = 0; kc < 16; kc++) {
        float4 xa = pxa[kc & 7];
        float4 xb = pxb[kc & 7];
        if (kc < 8) {
            pxa[kc & 7] = X4[xbase4 + (kc + 8) * 8 + kg * 2];
            pxb[kc & 7] = X4[xbase4 + (kc + 8) * 8 + kg * 2 + 1];
        }
        short8 af;
        af[0] = (short)f2bf(xa.x); af[1] = (short)f2bf(xa.y);
        af[2] = (short)f2bf(xa.z); af[3] = (short)f2bf(xa.w);
        af[4] = (short)f2bf(xb.x); af[5] = (short)f2bf(xb.y);
        af[6] = (short)f2bf(xb.z); af[7] = (short)f2bf(xb.w);
#pragma unroll
        for (int mt = 0; mt < 4; mt++) {
            short8 bfr = Qb8[qfrag + (kc * 4 + mt) * 64];
            acc[mt] = __builtin_amdgcn_mfma_f32_16x16x32_bf16(af, bfr, acc[mt], 0, 0, 0);
        }
    }
    const float* cb = ws + OFF_CB + b * 64;
    unsigned short* LGB = (unsigned short*)(ws + OFF_LGB) + b * (N_ * 64) + nt * 16 * 64;
#pragma unroll
    for (int mt = 0; mt < 4; mt++) {
        int m = mt * 16 + col;
        float c = cb[m];
        float v0 = acc[mt][0] + c, v1 = acc[mt][1] + c;
        float v2 = acc[mt][2] + c, v3 = acc[mt][3] + c;
        int nr = kg * 4;
        LGB[(nr + 0) * 64 + m] = f2bf(v0);
        LGB[(nr + 1) * 64 + m] = f2bf(v1);
        LGB[(nr + 2) * 64 + m] = f2bf(v2);
        LGB[(nr + 3) * 64 + m] = f2bf(v3);
        float mx = fmaxf(fmaxf(v0, v1), fmaxf(v2, v3));
        mx = fmaxf(mx, __shfl_xor(mx, 16));
        mx = fmaxf(mx, __shfl_xor(mx, 32));
        float s = expf(v0 - mx) + expf(v1 - mx) + expf(v2 - mx) + expf(v3 - mx);
        s += __shfl_xor(s, 16);
        s += __shfl_xor(s, 32);
        if (kg == 0) {
            ws[OFF_TPMAX + (b * 64 + m) * 256 + nt] = mx;
            ws[OFF_TPSUM + (b * 64 + m) * 256 + nt] = s;
        }
    }
}

// ---- K6: combine partials -> gmax, 1/denom. wave per (b,m). grid 256, block 256 ----
__global__ __launch_bounds__(256) void k_combine(float* __restrict__ ws) {
    int t = threadIdx.x;
    int w = blockIdx.x * 4 + (t >> 6);   // 0..1023 = b*64+m
    int l = t & 63;
    float4 a  = ((const float4*)(ws + OFF_TPMAX + w * 256))[l];
    float4 s4 = ((const float4*)(ws + OFF_TPSUM + w * 256))[l];
    float g = fmaxf(fmaxf(a.x, a.y), fmaxf(a.z, a.w));
    float s = s4.x * expf(a.x - g) + s4.y * expf(a.y - g)
            + s4.z * expf(a.z - g) + s4.w * expf(a.w - g);
#pragma unroll
    for (int off = 1; off < 64; off <<= 1) {
        float og = __shfl_xor(g, off);
        float os = __shfl_xor(s, off);
        float ng = fmaxf(g, og);
        s = s * expf(g - ng) + os * expf(og - ng);
        g = ng;
    }
    if (l == 0) { ws[OFF_GMAX + w] = g; ws[OFF_GINV + w] = 1.0f / s; }
}

// ---- K7: out = exp(bf16(l) - gmax) * ginv. grid 2048, block 256 (8 elems/thread) ----
__global__ __launch_bounds__(256) void k_final(const float* __restrict__ ws, float* __restrict__ out) {
    int idx = blockIdx.x * 256 + threadIdx.x;   // uint4 (8 bf16) index
    int flat = idx * 8;
    int b = flat >> 18;                         // / (4096*64)
    int m0 = flat & 63;                         // multiple of 8
    uint4 lg = ((const uint4*)((const unsigned short*)(ws + OFF_LGB)))[idx];
    int bm = b * 64 + m0;
    float4 ga = *(const float4*)(ws + OFF_GMAX + bm);
    float4 gb = *(const float4*)(ws + OFF_GMAX + bm + 4);
    float4 ia = *(const float4*)(ws + OFF_GINV + bm);
    float4 ib = *(const float4*)(ws + OFF_GINV + bm + 4);
    float4 o0, o1;
    o0.x = expf(__uint_as_float(lg.x << 16)         - ga.x) * ia.x;
    o0.y = expf(__uint_as_float(lg.x & 0xffff0000u) - ga.y) * ia.y;
    o0.z = expf(__uint_as_float(lg.y << 16)         - ga.z) * ia.z;
    o0.w = expf(__uint_as_float(lg.y & 0xffff0000u) - ga.w) * ia.w;
    o1.x = expf(__uint_as_float(lg.z << 16)         - gb.x) * ib.x;
    o1.y = expf(__uint_as_float(lg.z & 0xffff0000u) - gb.y) * ib.y;
    o1.z = expf(__uint_as_float(lg.w << 16)         - gb.z) * ib.z;
    o1.w = expf(__uint_as_float(lg.w & 0xffff0000u) - gb.w) * ib.w;
    ((float4*)out)[idx * 2]     = o0;
    ((float4*)out)[idx * 2 + 1] = o1;
}

extern "C" void kernel_launch(void* const* d_in, const int* in_sizes, int n_in,
                              void* d_out, int out_size, void* d_ws, size_t ws_size,
                              hipStream_t stream) {
    const float* X  = (const float*)d_in[0];
    const float* pb = (const float*)d_in[1];
    const float* Wc = (const float*)d_in[2];
    const float* bc = (const float*)d_in[3];
    const float* Wp = (const float*)d_in[4];
    const float* bp = (const float*)d_in[5];
    float* ws  = (float*)d_ws;
    float* out = (float*)d_out;

    k_pool<<<1024, 256, 0, stream>>>(X, ws);
    k_prep<<<128, 256, 0, stream>>>(Wp, ws);
    k_protos<<<512, 256, 0, stream>>>(Wc, pb, bc, ws);
    k_q<<<512, 256, 0, stream>>>(bp, ws);
    k_logits<<<1024, 256, 0, stream>>>(X, ws);
    k_combine<<<256, 256, 0, stream>>>(ws);
    k_final<<<2048, 256, 0, stream>>>(ws, out);
}

// Round 20
// 117.630 us; speedup vs baseline: 3.3929x; 1.0118x over previous
//
#include <hip/hip_runtime.h>
#include <math.h>

#define B_ 16
#define N_ 4096
#define D_ 512
#define M_ 64
#define MD 32768   // M_*D_

typedef __attribute__((ext_vector_type(4))) float f32x4;
typedef __attribute__((ext_vector_type(8))) short short8;

// ---- workspace layout (float offsets) ----
#define OFF_PSUM   0          // [16][128][512] pooling sum partials (1048576)
#define OFF_PMAXP  1048576    // [16][128][512] pooling max partials (1048576)
#define OFF_CTXB   2097152    // bf16 [16][1024] ctx (8192)
#define OFF_PB     2105344    // bf16 P[b][m*512+d] (262144 floats worth)
#define OFF_WPT    2367488    // bf16 WpT[j][d] = Wp[d][j] (131072)
#define OFF_CB     2498560    // [16][64]
#define OFF_GMAX   2499584    // [16][64]
#define OFF_GINV   2500608    // [16][64]
#define OFF_TPMAX  2501632    // [1024][256] (262144)
#define OFF_TPSUM  2763776    // [1024][256] (262144)
#define OFF_QB     3025920    // bf16 Q' FRAGMENT-MAJOR [b][kc][mt][lane] short8 (262144 floats)
#define OFF_LGB    3288064    // bf16 [16][4096][64] (2097152)
// total = 5385216 floats = 21.5 MB

__device__ __forceinline__ unsigned short f2bf(float f) {
    unsigned int u = __float_as_uint(f);
    u += 0x7fffu + ((u >> 16) & 1u);   // round-to-nearest-even
    return (unsigned short)(u >> 16);
}
__device__ __forceinline__ float bf2f(unsigned short u) {
    return __uint_as_float(((unsigned int)u) << 16);
}

// ---- K1: pooling partials. grid 1024 (b*64+nc), block 256 ----
__global__ __launch_bounds__(256) void k_pool(const float* __restrict__ X, float* __restrict__ ws) {
    int b = blockIdx.x >> 6, nc = blockIdx.x & 63, t = threadIdx.x;
    int c = t & 127, p = t >> 7;
    const float4* X4 = (const float4*)X;
    float4 s = make_float4(0.f, 0.f, 0.f, 0.f);
    float4 mx = make_float4(-INFINITY, -INFINITY, -INFINITY, -INFINITY);
    int rowbase = b * N_ + nc * 64 + p;
#pragma unroll 8
    for (int i = 0; i < 32; i++) {
        int n = rowbase + 2 * i;
        float4 v = X4[n * 128 + c];
        s.x += v.x; s.y += v.y; s.z += v.z; s.w += v.w;
        mx.x = fmaxf(mx.x, v.x); mx.y = fmaxf(mx.y, v.y);
        mx.z = fmaxf(mx.z, v.z); mx.w = fmaxf(mx.w, v.w);
    }
    int slot = (b * 128 + nc * 2 + p) * 128 + c;   // float4 units
    ((float4*)(ws + OFF_PSUM))[slot] = s;
    ((float4*)(ws + OFF_PMAXP))[slot] = mx;
}

// ---- K2: prep. blocks 0-63: ctx finalize. blocks 64-127: Wp transpose. ----
__global__ __launch_bounds__(256) void k_prep(const float* __restrict__ Wp, float* __restrict__ ws) {
    __shared__ __align__(16) char smem[8448];
    int bx = blockIdx.x, t = threadIdx.x;
    if (bx < 64) {
        f32x4* red = (f32x4*)smem;
        int b = bx >> 2, q = bx & 3;
        int lane = t & 63, w = t >> 6;
        bool isMax = (q >= 2);
        const f32x4* SRC = (const f32x4*)(ws + (isMax ? OFF_PMAXP : OFF_PSUM));
        int kk = (q & 1) * 64 + lane;
        f32x4 acc;
        if (isMax) acc = (f32x4){-INFINITY, -INFINITY, -INFINITY, -INFINITY};
        else       acc = (f32x4){0.f, 0.f, 0.f, 0.f};
#pragma unroll 8
        for (int i = 0; i < 32; i++) {
            int c = w * 32 + i;
            f32x4 v = SRC[(b * 128 + c) * 128 + kk];
            if (isMax) {
                acc[0] = fmaxf(acc[0], v[0]); acc[1] = fmaxf(acc[1], v[1]);
                acc[2] = fmaxf(acc[2], v[2]); acc[3] = fmaxf(acc[3], v[3]);
            } else {
                acc[0] += v[0]; acc[1] += v[1]; acc[2] += v[2]; acc[3] += v[3];
            }
        }
        red[t] = acc;
        __syncthreads();
        if (t < 64) {
            f32x4 a = red[t], b1 = red[64 + t], c1 = red[128 + t], d = red[192 + t];
            f32x4 r;
            if (isMax) {
#pragma unroll
                for (int j = 0; j < 4; j++) r[j] = fmaxf(fmaxf(a[j], b1[j]), fmaxf(c1[j], d[j]));
            } else {
#pragma unroll
                for (int j = 0; j < 4; j++) r[j] = (a[j] + b1[j] + c1[j] + d[j]) * (1.0f / 4096.0f);
            }
            ushort4 o;
            o.x = f2bf(r[0]); o.y = f2bf(r[1]); o.z = f2bf(r[2]); o.w = f2bf(r[3]);
            ((ushort4*)(ws + OFF_CTXB))[b * 256 + q * 64 + t] = o;
        }
    } else {
        unsigned short (*lt)[65] = (unsigned short(*)[65])smem;
        int bb = bx - 64;
        int ti = bb >> 3, tj = bb & 7;
        int sub = t >> 6, lane = t & 63;
#pragma unroll
        for (int i = 0; i < 16; i++) {
            int dl = i * 4 + sub;
            int jl = lane;
            lt[jl][dl] = f2bf(Wp[(ti * 64 + dl) * 512 + tj * 64 + jl]);
        }
        __syncthreads();
        unsigned short* WT = (unsigned short*)(ws + OFF_WPT);
#pragma unroll
        for (int i = 0; i < 16; i++) {
            int jl = i * 4 + sub;
            int dl = lane;
            WT[(tj * 64 + jl) * 512 + ti * 64 + dl] = lt[jl][dl];
        }
    }
}

// ---- K3: P via MFMA -> bf16 Pb. grid 512, block 256. NT loads. ----
__global__ __launch_bounds__(256) void k_protos(const float* __restrict__ Wc, const float* __restrict__ pb,
                                                const float* __restrict__ bc, float* __restrict__ ws) {
    int t = threadIdx.x;
    int wave = blockIdx.x * 4 + (t >> 6);   // 0..2047 tiles of 16 W-rows
    int l = t & 63;
    int r0 = wave * 16;
    int row = r0 + (l & 15);                // this lane's W-row (B-frag col)
    int kg = l >> 4;
    const f32x4* W4 = (const f32x4*)Wc;                    // row stride 256 float4
    const short8* CB8 = (const short8*)(ws + OFF_CTXB);    // [16][128] short8 units
    f32x4 acc = (f32x4){0.f, 0.f, 0.f, 0.f};
    int wb = row * 256 + kg * 2;            // float4 idx: k = kg*8
    int cbase = (l & 15) * 128 + kg;        // A-frag: lane&15 = batch row
#pragma unroll 8
    for (int kc = 0; kc < 32; kc++) {
        f32x4 xa = __builtin_nontemporal_load(W4 + wb + kc * 8);
        f32x4 xb = __builtin_nontemporal_load(W4 + wb + kc * 8 + 1);
        short8 wf;
        wf[0] = (short)f2bf(xa[0]); wf[1] = (short)f2bf(xa[1]);
        wf[2] = (short)f2bf(xa[2]); wf[3] = (short)f2bf(xa[3]);
        wf[4] = (short)f2bf(xb[0]); wf[5] = (short)f2bf(xb[1]);
        wf[6] = (short)f2bf(xb[2]); wf[7] = (short)f2bf(xb[3]);
        short8 cf = CB8[cbase + kc * 4];
        acc = __builtin_amdgcn_mfma_f32_16x16x32_bf16(cf, wf, acc, 0, 0, 0);  // A=ctx, B=W
    }
    int r = r0 + (l & 15);
    float add = pb[r] + bc[r];
    unsigned short* Pb = (unsigned short*)(ws + OFF_PB);
#pragma unroll
    for (int i = 0; i < 4; i++) {
        int bb = kg * 4 + i;                // batch
        Pb[bb * MD + r] = f2bf(acc[i] + add);
    }
}

// ---- K4: Q' MFMA -> fragment-major Qb + c' fold (blocks 0-255). grid 512, block 256 ----
__global__ __launch_bounds__(256) void k_q(const float* __restrict__ bpre, float* __restrict__ ws) {
    int t = threadIdx.x;
    int b = blockIdx.x >> 5, ctile = blockIdx.x & 31;
    int mt = t >> 6, l = t & 63;
    int col = l & 15, kg = l >> 4;
    const short8* WT8 = (const short8*)((const unsigned short*)(ws + OFF_WPT));
    const short8* Pb8 = (const short8*)((const unsigned short*)(ws + OFF_PB));
    f32x4 acc = (f32x4){0.f, 0.f, 0.f, 0.f};
    int abase = (ctile * 16 + col) * 64 + kg;        // A: WpT row = j, k = d
    int bbase = (b * 64 + mt * 16 + col) * 64 + kg;  // B: P row = m, k = d
#pragma unroll 4
    for (int kc = 0; kc < 16; kc++) {
        short8 af = WT8[abase + kc * 4];
        short8 bf = Pb8[bbase + kc * 4];
        acc = __builtin_amdgcn_mfma_f32_16x16x32_bf16(af, bf, acc, 0, 0, 0);
    }
    // D[j = ctile*16 + kg*4 + i][m = mt*16+col] -> fragment-major Qb
    union { unsigned short u[4]; uint2 v; } pk;
#pragma unroll
    for (int i = 0; i < 4; i++) pk.u[i] = f2bf(acc[i] * (1.0f / 64.0f));
    int g = (ctile & 1) * 2 + (kg >> 1);
    int fidx = b * 4096 + ((ctile >> 1) * 4 + mt) * 64 + g * 16 + col;   // short8 units
    ((uint2*)((unsigned short*)(ws + OFF_QB)))[fidx * 2 + (kg & 1)] = pk.v;

    if (blockIdx.x < 256) {                 // c'[b][m] fold
        int w = blockIdx.x * 4 + (t >> 6);  // 0..1023 = b*64+m
        int bb = w >> 6, mm = w & 63;
        const short8* P2 = (const short8*)((const unsigned short*)(ws + OFF_PB) + bb * MD + mm * 512);
        short8 p = P2[l];
        const float4* bp4 = (const float4*)bpre;
        float4 q0 = bp4[l * 2], q1 = bp4[l * 2 + 1];
        float s = bf2f((unsigned short)p[0]) * q0.x + bf2f((unsigned short)p[1]) * q0.y
                + bf2f((unsigned short)p[2]) * q0.z + bf2f((unsigned short)p[3]) * q0.w
                + bf2f((unsigned short)p[4]) * q1.x + bf2f((unsigned short)p[5]) * q1.y
                + bf2f((unsigned short)p[6]) * q1.z + bf2f((unsigned short)p[7]) * q1.w;
#pragma unroll
        for (int off = 1; off < 64; off <<= 1) s += __shfl_xor(s, off);
        if (l == 0) ws[OFF_CB + w] = s * (1.0f / 64.0f);
    }
}

// ---- K5: logits via MFMA; X staged through XOR-swizzled LDS (kills A-frag scatter). ----
// grid 2048 = b(16) x ntp(128); block 256 = 4 waves; wave = nt (ntp*2+(w&1)) x 2 mt.
__global__ __launch_bounds__(256) void k_logits(const float* __restrict__ X, float* __restrict__ ws) {
    __shared__ unsigned short xls[16384];   // [32 rows][512 cols] bf16, swizzled, 32 KB
    int t = threadIdx.x;
    int b = blockIdx.x >> 7, ntp = blockIdx.x & 127;

    // stage: 32 rows x 512 cols fp32 -> bf16 LDS (coalesced 1KB/instr reads)
    const float4* X4 = (const float4*)X;
    int xrowbase = (b * N_ + ntp * 32) * 128;    // float4 units
#pragma unroll
    for (int j = 0; j < 16; j++) {
        int flat = j * 256 + t;                  // quad index 0..4095
        int row = flat >> 7, qc = flat & 127;
        float4 v = X4[xrowbase + row * 128 + qc];
        ushort4 o;
        o.x = f2bf(v.x); o.y = f2bf(v.y); o.z = f2bf(v.z); o.w = f2bf(v.w);
        int byte = (row << 10) + ((qc << 3) ^ ((row & 7) << 4));
        *(ushort4*)((char*)xls + byte) = o;
    }
    __syncthreads();

    int w = t >> 6, l = t & 63, col = l & 15, kg = l >> 4;
    int ntl = w & 1;
    int nt = ntp * 2 + ntl;
    int mt0 = (w >> 1) * 2;
    const short8* Qb8 = (const short8*)((const unsigned short*)(ws + OFF_QB));
    int qfrag = b * 4096 + l;
    f32x4 acc[2];
    acc[0] = (f32x4){0.f, 0.f, 0.f, 0.f};
    acc[1] = (f32x4){0.f, 0.f, 0.f, 0.f};
    int rl = ntl * 16 + col;                     // local row 0..31
    int rhi = rl << 10, rx = (rl & 7) << 4;
#pragma unroll
    for (int kc = 0; kc < 16; kc++) {
        short8 af = *(const short8*)((const char*)xls + rhi + (((kc << 6) + (kg << 4)) ^ rx));
#pragma unroll
        for (int mi = 0; mi < 2; mi++) {
            short8 bfr = Qb8[qfrag + (kc * 4 + mt0 + mi) * 64];
            acc[mi] = __builtin_amdgcn_mfma_f32_16x16x32_bf16(af, bfr, acc[mi], 0, 0, 0);
        }
    }
    const float* cb = ws + OFF_CB + b * 64;
    unsigned short* LGB = (unsigned short*)(ws + OFF_LGB) + b * (N_ * 64) + nt * 16 * 64;
#pragma unroll
    for (int mi = 0; mi < 2; mi++) {
        int m = (mt0 + mi) * 16 + col;
        float c = cb[m];
        float v0 = acc[mi][0] + c, v1 = acc[mi][1] + c;
        float v2 = acc[mi][2] + c, v3 = acc[mi][3] + c;
        int nr = kg * 4;
        LGB[(nr + 0) * 64 + m] = f2bf(v0);
        LGB[(nr + 1) * 64 + m] = f2bf(v1);
        LGB[(nr + 2) * 64 + m] = f2bf(v2);
        LGB[(nr + 3) * 64 + m] = f2bf(v3);
        float mx = fmaxf(fmaxf(v0, v1), fmaxf(v2, v3));
        mx = fmaxf(mx, __shfl_xor(mx, 16));
        mx = fmaxf(mx, __shfl_xor(mx, 32));
        float s = expf(v0 - mx) + expf(v1 - mx) + expf(v2 - mx) + expf(v3 - mx);
        s += __shfl_xor(s, 16);
        s += __shfl_xor(s, 32);
        if (kg == 0) {
            ws[OFF_TPMAX + (b * 64 + m) * 256 + nt] = mx;
            ws[OFF_TPSUM + (b * 64 + m) * 256 + nt] = s;
        }
    }
}

// ---- K6: combine partials -> gmax, 1/denom. wave per (b,m). grid 256, block 256 ----
__global__ __launch_bounds__(256) void k_combine(float* __restrict__ ws) {
    int t = threadIdx.x;
    int w = blockIdx.x * 4 + (t >> 6);   // 0..1023 = b*64+m
    int l = t & 63;
    float4 a  = ((const float4*)(ws + OFF_TPMAX + w * 256))[l];
    float4 s4 = ((const float4*)(ws + OFF_TPSUM + w * 256))[l];
    float g = fmaxf(fmaxf(a.x, a.y), fmaxf(a.z, a.w));
    float s = s4.x * expf(a.x - g) + s4.y * expf(a.y - g)
            + s4.z * expf(a.z - g) + s4.w * expf(a.w - g);
#pragma unroll
    for (int off = 1; off < 64; off <<= 1) {
        float og = __shfl_xor(g, off);
        float os = __shfl_xor(s, off);
        float ng = fmaxf(g, og);
        s = s * expf(g - ng) + os * expf(og - ng);
        g = ng;
    }
    if (l == 0) { ws[OFF_GMAX + w] = g; ws[OFF_GINV + w] = 1.0f / s; }
}

// ---- K7: out = exp(bf16(l) - gmax) * ginv. grid 2048, block 256 (8 elems/thread) ----
__global__ __launch_bounds__(256) void k_final(const float* __restrict__ ws, float* __restrict__ out) {
    int idx = blockIdx.x * 256 + threadIdx.x;   // uint4 (8 bf16) index
    int flat = idx * 8;
    int b = flat >> 18;                         // / (4096*64)
    int m0 = flat & 63;                         // multiple of 8
    uint4 lg = ((const uint4*)((const unsigned short*)(ws + OFF_LGB)))[idx];
    int bm = b * 64 + m0;
    float4 ga = *(const float4*)(ws + OFF_GMAX + bm);
    float4 gb = *(const float4*)(ws + OFF_GMAX + bm + 4);
    float4 ia = *(const float4*)(ws + OFF_GINV + bm);
    float4 ib = *(const float4*)(ws + OFF_GINV + bm + 4);
    float4 o0, o1;
    o0.x = expf(__uint_as_float(lg.x << 16)         - ga.x) * ia.x;
    o0.y = expf(__uint_as_float(lg.x & 0xffff0000u) - ga.y) * ia.y;
    o0.z = expf(__uint_as_float(lg.y << 16)         - ga.z) * ia.z;
    o0.w = expf(__uint_as_float(lg.y & 0xffff0000u) - ga.w) * ia.w;
    o1.x = expf(__uint_as_float(lg.z << 16)         - gb.x) * ib.x;
    o1.y = expf(__uint_as_float(lg.z & 0xffff0000u) - gb.y) * ib.y;
    o1.z = expf(__uint_as_float(lg.w << 16)         - gb.z) * ib.z;
    o1.w = expf(__uint_as_float(lg.w & 0xffff0000u) - gb.w) * ib.w;
    ((float4*)out)[idx * 2]     = o0;
    ((float4*)out)[idx * 2 + 1] = o1;
}

extern "C" void kernel_launch(void* const* d_in, const int* in_sizes, int n_in,
                              void* d_out, int out_size, void* d_ws, size_t ws_size,
                              hipStream_t stream) {
    const float* X  = (const float*)d_in[0];
    const float* pb = (const float*)d_in[1];
    const float* Wc = (const float*)d_in[2];
    const float* bc = (const float*)d_in[3];
    const float* Wp = (const float*)d_in[4];
    const float* bp = (const float*)d_in[5];
    float* ws  = (float*)d_ws;
    float* out = (float*)d_out;

    k_pool<<<1024, 256, 0, stream>>>(X, ws);
    k_prep<<<128, 256, 0, stream>>>(Wp, ws);
    k_protos<<<512, 256, 0, stream>>>(Wc, pb, bc, ws);
    k_q<<<512, 256, 0, stream>>>(bp, ws);
    k_logits<<<2048, 256, 0, stream>>>(X, ws);
    k_combine<<<256, 256, 0, stream>>>(ws);
    k_final<<<2048, 256, 0, stream>>>(ws, out);
}